// Round 3
// baseline (181.438 us; speedup 1.0000x reference)
//
#include <hip/hip_runtime.h>

// BERT lattice embedding: ragged segment mean-pool.
// hidden: [B,S,H] f32, word_ids: [B,S] i32 (non-decreasing per sample),
// out: [B,T,H] f32 with out[b,t,:] = mean over the contiguous run of s with
// word_ids[b,s]==t (zeros if the run is empty).
//
// R2 design: streaming. One 192-thread block (3 waves) per (b, 16-word chunk).
// The chunk's pieces occupy one contiguous row span [spanlo, spanhi); spans of
// different chunks are disjoint, so every hidden row is read exactly once,
// sequentially. Thread tid owns float4 column tid (192*16B = 3KB/row).
// Depth-2 prefetch keeps loads unconditional and back-to-back (no per-row
// vmcnt(0) stall). All run-boundary logic is block-uniform (no divergence).
// Empty words get a zero-fill epilogue from the boundary tables.

#define BB 64
#define SS 512
#define HH 768
#define TT 400
#define TCHUNK 16
#define NCHUNK (TT / TCHUNK)     // 25
#define NTHR 192                 // 3 waves; 192 float4 = 768 floats = H
#define H4 (HH / 4)              // 192

__global__ __launch_bounds__(NTHR) void bert_lattice_pool_kernel(
    const float* __restrict__ hidden,
    const int* __restrict__ word_ids,
    float* __restrict__ out)
{
    __shared__ int wid[SS];
    __shared__ int sstart[TCHUNK];
    __shared__ int send[TCHUNK];
    __shared__ int spanlo_s;
    __shared__ int spanhi_s;

    const int blk = blockIdx.x;             // b * NCHUNK + chunk
    const int b   = blk / NCHUNK;
    const int t0  = (blk - b * NCHUNK) * TCHUNK;
    const int t1  = t0 + TCHUNK;
    const int tid = threadIdx.x;

    // Stage word_ids row into LDS; init tables.
    for (int i = tid; i < SS; i += NTHR) wid[i] = word_ids[b * SS + i];
    if (tid < TCHUNK) { sstart[tid] = 0; send[tid] = 0; }
    if (tid == 0) { spanlo_s = SS; spanhi_s = 0; }
    __syncthreads();

    // Parallel boundary scatter. Unique writers for each slot (runs are
    // contiguous), so no races.
    for (int s = tid; s < SS; s += NTHR) {
        const int w = wid[s];
        if (w >= t0 && w < t1) {
            if (s == 0      || wid[s - 1] != w) sstart[w - t0] = s;
            if (s == SS - 1 || wid[s + 1] != w) send[w - t0]   = s + 1;
            if (s == 0      || wid[s - 1] < t0) spanlo_s = s;        // first in-chunk s
        }
        if (w < t1 && (s == SS - 1 || wid[s + 1] >= t1)) spanhi_s = s + 1;  // last s with wid<t1
    }
    __syncthreads();

    const int spanlo = spanlo_s;
    const int spanhi = spanhi_s;   // empty chunk: spanlo=SS >= spanhi -> loop skipped

    const float4* hbase = reinterpret_cast<const float4*>(hidden) + (size_t)b * SS * H4;
    float4*       obase = reinterpret_cast<float4*>(out)          + (size_t)b * TT * H4;

    if (spanlo < spanhi) {
        float4 acc = make_float4(0.f, 0.f, 0.f, 0.f);
        int run_start = spanlo;

        float4 v = hbase[(size_t)spanlo * H4 + tid];
        for (int s = spanlo; s < spanhi; ++s) {
            // Unconditional prefetch of next row (clamped address) — keeps the
            // load stream flowing without a per-iteration uniform branch.
            const int sn = (s + 1 < spanhi) ? (s + 1) : s;
            float4 vn = hbase[(size_t)sn * H4 + tid];

            acc.x += v.x; acc.y += v.y; acc.z += v.z; acc.w += v.w;

            const int w = wid[s];                       // block-uniform
            const bool endrun = (s + 1 == spanhi) || (wid[s + 1] != w);
            if (endrun) {                               // uniform branch
                const float inv = 1.0f / (float)(s - run_start + 1);
                obase[(size_t)w * H4 + tid] =
                    make_float4(acc.x * inv, acc.y * inv, acc.z * inv, acc.w * inv);
                acc = make_float4(0.f, 0.f, 0.f, 0.f);
                run_start = s + 1;
            }
            v = vn;
        }
    }

    // Zero-fill words with no pieces (sstart==send==0 only when empty).
    #pragma unroll
    for (int rel = 0; rel < TCHUNK; ++rel) {
        if (send[rel] == sstart[rel]) {
            obase[(size_t)(t0 + rel) * H4 + tid] = make_float4(0.f, 0.f, 0.f, 0.f);
        }
    }
}

extern "C" void kernel_launch(void* const* d_in, const int* in_sizes, int n_in,
                              void* d_out, int out_size, void* d_ws, size_t ws_size,
                              hipStream_t stream) {
    (void)in_sizes; (void)n_in; (void)d_ws; (void)ws_size; (void)out_size;
    const float* hidden   = (const float*)d_in[0];
    const int*   word_ids = (const int*)d_in[1];
    float*       out      = (float*)d_out;

    dim3 grid(BB * NCHUNK);   // 64 * 25 = 1600 blocks
    dim3 block(NTHR);
    bert_lattice_pool_kernel<<<grid, block, 0, stream>>>(hidden, word_ids, out);
}